// Round 1
// baseline (3177.045 us; speedup 1.0000x reference)
//
#include <hip/hip_runtime.h>
#include <math.h>

// Problem constants (match reference)
#define NN 50000
#define FIN 512
#define HIDN 128
#define NCLS 16
#define NE 800000

// ---------------- degree / dinv ----------------

__global__ void init_deg_kernel(float* __restrict__ deg, int n) {
    int i = blockIdx.x * blockDim.x + threadIdx.x;
    if (i < n) deg[i] = 1.0f;  // self-loop contributes 1
}

__global__ void accum_deg_kernel(const int* __restrict__ dst, float* __restrict__ deg, int e) {
    int i = blockIdx.x * blockDim.x + threadIdx.x;
    if (i < e) atomicAdd(&deg[dst[i]], 1.0f);
}

__global__ void dinv_kernel(const float* __restrict__ deg, float* __restrict__ dinv, int n) {
    int i = blockIdx.x * blockDim.x + threadIdx.x;
    if (i < n) dinv[i] = 1.0f / sqrtf(deg[i]);  // deg >= 1 always (self loop)
}

// ---------------- tiled f32 GEMM with dinv-scaled epilogue ----------------
// C[r][:] = (A[r][:] @ W) * dinv[r]
// block = 256 threads, tile BM x KOUT, BK=32, per-thread TM x TN register tile.

template<int KIN, int KOUT, int BM, int TM, int TN>
__global__ __launch_bounds__(256) void gemm_dinv_kernel(
    const float* __restrict__ A, const float* __restrict__ W,
    const float* __restrict__ dinv, float* __restrict__ C, int nrows) {
    constexpr int BK = 32;
    constexpr int CT = KOUT / TN;   // col thread-groups
    constexpr int RT = 256 / CT;    // row thread-groups
    static_assert(RT * TM == BM, "tile mismatch");

    __shared__ float sAT[BK][BM + 4];   // A transposed: sAT[k][row]
    __shared__ float sW[BK][KOUT];      // W chunk

    const int tid = threadIdx.x;
    const int tx = tid % CT;            // col group -> cols [tx*TN, tx*TN+TN)
    const int ty = tid / CT;            // row group -> rows [ty*TM, ty*TM+TM)
    const int row0 = blockIdx.x * BM;

    float acc[TM][TN];
#pragma unroll
    for (int r = 0; r < TM; ++r)
#pragma unroll
        for (int c = 0; c < TN; ++c) acc[r][c] = 0.0f;

    for (int k0 = 0; k0 < KIN; k0 += BK) {
        // --- stage A tile (BM x BK), transposed into sAT ---
        constexpr int AF4 = BM * BK / 4;
#pragma unroll
        for (int i = tid; i < AF4; i += 256) {
            int r = i / (BK / 4);
            int kq = i % (BK / 4);
            float4 v = make_float4(0.f, 0.f, 0.f, 0.f);
            int gr = row0 + r;
            if (gr < nrows)
                v = *(const float4*)&A[(size_t)gr * KIN + k0 + kq * 4];
            sAT[kq * 4 + 0][r] = v.x;
            sAT[kq * 4 + 1][r] = v.y;
            sAT[kq * 4 + 2][r] = v.z;
            sAT[kq * 4 + 3][r] = v.w;
        }
        // --- stage W tile (BK x KOUT) ---
        constexpr int WF4 = BK * KOUT / 4;
#pragma unroll
        for (int i = tid; i < WF4; i += 256) {
            int k = i / (KOUT / 4);
            int c = i % (KOUT / 4);
            *(float4*)&sW[k][c * 4] = *(const float4*)&W[(size_t)(k0 + k) * KOUT + c * 4];
        }
        __syncthreads();

#pragma unroll
        for (int k = 0; k < BK; ++k) {
            float a[TM];
            float w[TN];
            *(float4*)&a[0] = *(const float4*)&sAT[k][ty * TM];
#pragma unroll
            for (int j = 0; j < TN; j += 4)
                *(float4*)&w[j] = *(const float4*)&sW[k][tx * TN + j];
#pragma unroll
            for (int r = 0; r < TM; ++r)
#pragma unroll
                for (int c = 0; c < TN; ++c)
                    acc[r][c] = fmaf(a[r], w[c], acc[r][c]);
        }
        __syncthreads();
    }

    // --- epilogue: scale by dinv[row], store ---
#pragma unroll
    for (int r = 0; r < TM; ++r) {
        int gr = row0 + ty * TM + r;
        if (gr < nrows) {
            float s = dinv[gr];
#pragma unroll
            for (int c = 0; c < TN; c += 4) {
                float4 v;
                v.x = acc[r][c + 0] * s;
                v.y = acc[r][c + 1] * s;
                v.z = acc[r][c + 2] * s;
                v.w = acc[r][c + 3] * s;
                *(float4*)&C[(size_t)gr * KOUT + tx * TN + c] = v;
            }
        }
    }
}

// ---------------- self-loop init: agg[i] = hs[i] * dinv[i] ----------------
// (hs already carries one dinv factor, so this gives dinv^2 * h == self-loop norm)

__global__ void self_init_kernel(const float* __restrict__ hs, const float* __restrict__ dinv,
                                 float* __restrict__ agg, int n, int kout) {
    int idx = blockIdx.x * blockDim.x + threadIdx.x;   // float4 index
    int kq = kout / 4;
    int total = n * kq;
    if (idx < total) {
        int row = idx / kq;
        float s = dinv[row];
        float4 v = ((const float4*)hs)[idx];
        v.x *= s; v.y *= s; v.z *= s; v.w *= s;
        ((float4*)agg)[idx] = v;
    }
}

// ---------------- edge scatter: agg[dst] += hs[src] * dinv[dst] ----------------

template<int KOUT>
__global__ __launch_bounds__(256) void scatter_kernel(
    const int* __restrict__ srcs, const int* __restrict__ dsts,
    const float* __restrict__ dinv, const float* __restrict__ hs,
    float* __restrict__ agg, int e) {
    constexpr int LPE = KOUT / 4;       // lanes per edge (float4 each)
    constexpr int EPB = 256 / LPE;      // edges per block
    int eid = blockIdx.x * EPB + threadIdx.x / LPE;
    int lane = threadIdx.x % LPE;
    if (eid >= e) return;
    int s = srcs[eid];
    int d = dsts[eid];
    float w = dinv[d];                  // hs already has dinv[src]
    float4 v = *(const float4*)&hs[(size_t)s * KOUT + lane * 4];
    float* o = &agg[(size_t)d * KOUT + lane * 4];
    atomicAdd(o + 0, v.x * w);
    atomicAdd(o + 1, v.y * w);
    atomicAdd(o + 2, v.z * w);
    atomicAdd(o + 3, v.w * w);
}

// ---------------- bias + optional relu ----------------

template<bool RELU>
__global__ void bias_act_kernel(const float* __restrict__ agg, const float* __restrict__ b,
                                float* __restrict__ out, int n, int kout) {
    int idx = blockIdx.x * blockDim.x + threadIdx.x;   // float4 index
    int kq = kout / 4;
    if (idx < n * kq) {
        int c4 = idx % kq;
        float4 bb = ((const float4*)b)[c4];
        float4 v = ((const float4*)agg)[idx];
        v.x += bb.x; v.y += bb.y; v.z += bb.z; v.w += bb.w;
        if (RELU) {
            v.x = fmaxf(v.x, 0.f); v.y = fmaxf(v.y, 0.f);
            v.z = fmaxf(v.z, 0.f); v.w = fmaxf(v.w, 0.f);
        }
        ((float4*)out)[idx] = v;
    }
}

// ---------------- launch ----------------

extern "C" void kernel_launch(void* const* d_in, const int* in_sizes, int n_in,
                              void* d_out, int out_size, void* d_ws, size_t ws_size,
                              hipStream_t stream) {
    const float* x  = (const float*)d_in[0];
    const int* ei   = (const int*)d_in[1];       // [2][E]: first E = src, next E = dst
    const float* W0 = (const float*)d_in[2];
    const float* b0 = (const float*)d_in[3];
    const float* W1 = (const float*)d_in[4];
    const float* b1 = (const float*)d_in[5];
    const float* W2 = (const float*)d_in[6];
    const float* b2 = (const float*)d_in[7];
    float* out = (float*)d_out;

    const int* src = ei;
    const int* dst = ei + NE;

    // workspace layout (floats)
    float* ws   = (float*)d_ws;
    float* deg  = ws;                      // N
    float* dinv = ws + NN;                 // N
    float* bufA = ws + 2 * NN;             // N*128
    float* bufB = bufA + (size_t)NN * HIDN;// N*128

    const int B256 = 256;

    // degrees + dinv
    init_deg_kernel<<<(NN + 255) / 256, B256, 0, stream>>>(deg, NN);
    accum_deg_kernel<<<(NE + 255) / 256, B256, 0, stream>>>(dst, deg, NE);
    dinv_kernel<<<(NN + 255) / 256, B256, 0, stream>>>(deg, dinv, NN);

    // ---- layer 1: hs0 = (x @ W0) * dinv  -> bufA
    gemm_dinv_kernel<FIN, HIDN, 64, 4, 8><<<(NN + 63) / 64, B256, 0, stream>>>(x, W0, dinv, bufA, NN);
    // agg -> bufB
    self_init_kernel<<<(NN * HIDN / 4 + 255) / 256, B256, 0, stream>>>(bufA, dinv, bufB, NN, HIDN);
    scatter_kernel<HIDN><<<(NE + 7) / 8, B256, 0, stream>>>(src, dst, dinv, bufA, bufB, NE);
    // h1 = relu(agg + b0) -> bufA
    bias_act_kernel<true><<<(NN * HIDN / 4 + 255) / 256, B256, 0, stream>>>(bufB, b0, bufA, NN, HIDN);

    // ---- layer 2: hs1 = (h1 @ W1) * dinv -> bufB
    gemm_dinv_kernel<HIDN, HIDN, 64, 4, 8><<<(NN + 63) / 64, B256, 0, stream>>>(bufA, W1, dinv, bufB, NN);
    self_init_kernel<<<(NN * HIDN / 4 + 255) / 256, B256, 0, stream>>>(bufB, dinv, bufA, NN, HIDN);
    scatter_kernel<HIDN><<<(NE + 7) / 8, B256, 0, stream>>>(src, dst, dinv, bufB, bufA, NE);
    // h2 = relu(agg + b1) -> bufB
    bias_act_kernel<true><<<(NN * HIDN / 4 + 255) / 256, B256, 0, stream>>>(bufA, b1, bufB, NN, HIDN);

    // ---- layer 3: hs2 = (h2 @ W2) * dinv -> bufA (N x 16)
    gemm_dinv_kernel<HIDN, NCLS, 256, 4, 4><<<(NN + 255) / 256, B256, 0, stream>>>(bufB, W2, dinv, bufA, NN);
    // agg directly in d_out
    self_init_kernel<<<(NN * NCLS / 4 + 255) / 256, B256, 0, stream>>>(bufA, dinv, out, NN, NCLS);
    scatter_kernel<NCLS><<<(NE + 63) / 64, B256, 0, stream>>>(src, dst, dinv, bufA, out, NE);
    // out += b2 (no relu), in place
    bias_act_kernel<false><<<(NN * NCLS / 4 + 255) / 256, B256, 0, stream>>>(out, b2, out, NN, NCLS);
}

// Round 9
// 687.875 us; speedup vs baseline: 4.6186x; 4.6186x over previous
//
#include <hip/hip_runtime.h>
#include <math.h>

// Problem constants (match reference)
#define NN 50000
#define FIN 512
#define HIDN 128
#define NCLS 16
#define NE 800000

// ---------------- CSR build ----------------

__global__ void zero_cnt_kernel(int* __restrict__ cnt, int n) {
    int i = blockIdx.x * blockDim.x + threadIdx.x;
    if (i < n) cnt[i] = 0;
}

__global__ void count_kernel(const int* __restrict__ dst, int* __restrict__ cnt, int e) {
    int i = blockIdx.x * blockDim.x + threadIdx.x;
    if (i < e) atomicAdd(&cnt[dst[i]], 1);
}

// Single-block exclusive scan over cnt[0..n) -> offs, cursor; also dinv = 1/sqrt(cnt+1).
__global__ __launch_bounds__(1024) void scan_kernel(
    const int* __restrict__ cnt, int* __restrict__ offs, int* __restrict__ cursor,
    float* __restrict__ dinv, int n) {
    __shared__ int partial[1024];
    const int tid = threadIdx.x;
    const int chunk = (n + 1023) / 1024;
    const int b = tid * chunk;
    const int e = min(b + chunk, n);
    int sum = 0;
    for (int i = b; i < e; ++i) sum += cnt[i];
    partial[tid] = sum;
    __syncthreads();
    // Hillis-Steele inclusive scan over partials
    for (int off = 1; off < 1024; off <<= 1) {
        int t = (tid >= off) ? partial[tid - off] : 0;
        __syncthreads();
        partial[tid] += t;
        __syncthreads();
    }
    int base = partial[tid] - sum;   // exclusive prefix for this chunk
    int running = base;
    for (int i = b; i < e; ++i) {
        offs[i] = running;
        cursor[i] = running;
        dinv[i] = 1.0f / sqrtf((float)(cnt[i] + 1));   // +1 self loop
        running += cnt[i];
    }
    if (tid == 1023) offs[n] = partial[1023];
}

__global__ void fill_kernel(const int* __restrict__ src, const int* __restrict__ dst,
                            int* __restrict__ cursor, int* __restrict__ csr_src, int e) {
    int i = blockIdx.x * blockDim.x + threadIdx.x;
    if (i < e) {
        int pos = atomicAdd(&cursor[dst[i]], 1);
        csr_src[pos] = src[i];
    }
}

// ---------------- tiled f32 GEMM with dinv-scaled epilogue ----------------
// C[r][:] = (A[r][:] @ W) * dinv[r]

template<int KIN, int KOUT, int BM, int TM, int TN>
__global__ __launch_bounds__(256) void gemm_dinv_kernel(
    const float* __restrict__ A, const float* __restrict__ W,
    const float* __restrict__ dinv, float* __restrict__ C, int nrows) {
    constexpr int BK = 32;
    constexpr int CT = KOUT / TN;   // col thread-groups
    constexpr int RT = 256 / CT;    // row thread-groups
    static_assert(RT * TM == BM, "tile mismatch");

    __shared__ float sAT[BK][BM + 4];   // A transposed: sAT[k][row]
    __shared__ float sW[BK][KOUT];      // W chunk

    const int tid = threadIdx.x;
    const int tx = tid % CT;
    const int ty = tid / CT;
    const int row0 = blockIdx.x * BM;

    float acc[TM][TN];
#pragma unroll
    for (int r = 0; r < TM; ++r)
#pragma unroll
        for (int c = 0; c < TN; ++c) acc[r][c] = 0.0f;

    for (int k0 = 0; k0 < KIN; k0 += BK) {
        constexpr int AF4 = BM * BK / 4;
#pragma unroll
        for (int i = tid; i < AF4; i += 256) {
            int r = i / (BK / 4);
            int kq = i % (BK / 4);
            float4 v = make_float4(0.f, 0.f, 0.f, 0.f);
            int gr = row0 + r;
            if (gr < nrows)
                v = *(const float4*)&A[(size_t)gr * KIN + k0 + kq * 4];
            sAT[kq * 4 + 0][r] = v.x;
            sAT[kq * 4 + 1][r] = v.y;
            sAT[kq * 4 + 2][r] = v.z;
            sAT[kq * 4 + 3][r] = v.w;
        }
        constexpr int WF4 = BK * KOUT / 4;
#pragma unroll
        for (int i = tid; i < WF4; i += 256) {
            int k = i / (KOUT / 4);
            int c = i % (KOUT / 4);
            *(float4*)&sW[k][c * 4] = *(const float4*)&W[(size_t)(k0 + k) * KOUT + c * 4];
        }
        __syncthreads();

#pragma unroll
        for (int k = 0; k < BK; ++k) {
            float a[TM];
            float w[TN];
            *(float4*)&a[0] = *(const float4*)&sAT[k][ty * TM];
#pragma unroll
            for (int j = 0; j < TN; j += 4)
                *(float4*)&w[j] = *(const float4*)&sW[k][tx * TN + j];
#pragma unroll
            for (int r = 0; r < TM; ++r)
#pragma unroll
                for (int c = 0; c < TN; ++c)
                    acc[r][c] = fmaf(a[r], w[c], acc[r][c]);
        }
        __syncthreads();
    }

#pragma unroll
    for (int r = 0; r < TM; ++r) {
        int gr = row0 + ty * TM + r;
        if (gr < nrows) {
            float s = dinv[gr];
#pragma unroll
            for (int c = 0; c < TN; c += 4) {
                float4 v;
                v.x = acc[r][c + 0] * s;
                v.y = acc[r][c + 1] * s;
                v.z = acc[r][c + 2] * s;
                v.w = acc[r][c + 3] * s;
                *(float4*)&C[(size_t)gr * KOUT + tx * TN + c] = v;
            }
        }
    }
}

// ---------------- CSR aggregate + bias (+relu) ----------------
// out[d] = (hs[d] + sum_{s in N(d)} hs[s]) * dinv[d] + bias    (hs carries dinv[src])

// 128-wide: one 64-lane wave per node, float2 per lane. 2-deep ILP on the
// neighbor loop so consecutive gathers pipeline (loop is L2-latency-bound).
template<bool RELU>
__global__ __launch_bounds__(256) void aggregate128_kernel(
    const int* __restrict__ offs, const int* __restrict__ csr_src,
    const float* __restrict__ dinv, const float* __restrict__ hs,
    const float* __restrict__ bias, float* __restrict__ outp, int n) {
    int node = blockIdx.x * 4 + (threadIdx.x >> 6);
    int lane = threadIdx.x & 63;
    if (node >= n) return;
    int beg = offs[node], end = offs[node + 1];
    float2 acc0 = *(const float2*)&hs[(size_t)node * HIDN + lane * 2];  // self
    float2 acc1 = make_float2(0.f, 0.f);
    int j = beg;
    for (; j + 1 < end; j += 2) {
        int s0 = csr_src[j];
        int s1 = csr_src[j + 1];
        float2 v0 = *(const float2*)&hs[(size_t)s0 * HIDN + lane * 2];
        float2 v1 = *(const float2*)&hs[(size_t)s1 * HIDN + lane * 2];
        acc0.x += v0.x; acc0.y += v0.y;
        acc1.x += v1.x; acc1.y += v1.y;
    }
    if (j < end) {
        int s = csr_src[j];
        float2 v = *(const float2*)&hs[(size_t)s * HIDN + lane * 2];
        acc0.x += v.x; acc0.y += v.y;
    }
    float w = dinv[node];
    float2 bb = *(const float2*)&bias[lane * 2];
    float ox = (acc0.x + acc1.x) * w + bb.x;
    float oy = (acc0.y + acc1.y) * w + bb.y;
    if (RELU) { ox = fmaxf(ox, 0.f); oy = fmaxf(oy, 0.f); }
    *(float2*)&outp[(size_t)node * HIDN + lane * 2] = make_float2(ox, oy);
}

// 16-wide: 16 lanes per node, one float per lane.
__global__ __launch_bounds__(256) void aggregate16_kernel(
    const int* __restrict__ offs, const int* __restrict__ csr_src,
    const float* __restrict__ dinv, const float* __restrict__ hs,
    const float* __restrict__ bias, float* __restrict__ outp, int n) {
    int node = blockIdx.x * 16 + (threadIdx.x >> 4);
    int lane = threadIdx.x & 15;
    if (node >= n) return;
    int beg = offs[node], end = offs[node + 1];
    float acc0 = hs[(size_t)node * NCLS + lane];   // self
    float acc1 = 0.f;
    int j = beg;
    for (; j + 1 < end; j += 2) {
        int s0 = csr_src[j];
        int s1 = csr_src[j + 1];
        acc0 += hs[(size_t)s0 * NCLS + lane];
        acc1 += hs[(size_t)s1 * NCLS + lane];
    }
    if (j < end) acc0 += hs[(size_t)csr_src[j] * NCLS + lane];
    outp[(size_t)node * NCLS + lane] = (acc0 + acc1) * dinv[node] + bias[lane];
}

// ---------------- launch ----------------

extern "C" void kernel_launch(void* const* d_in, const int* in_sizes, int n_in,
                              void* d_out, int out_size, void* d_ws, size_t ws_size,
                              hipStream_t stream) {
    const float* x  = (const float*)d_in[0];
    const int* ei   = (const int*)d_in[1];       // [2][E]: first E = src, next E = dst
    const float* W0 = (const float*)d_in[2];
    const float* b0 = (const float*)d_in[3];
    const float* W1 = (const float*)d_in[4];
    const float* b1 = (const float*)d_in[5];
    const float* W2 = (const float*)d_in[6];
    const float* b2 = (const float*)d_in[7];
    float* out = (float*)d_out;

    const int* src = ei;
    const int* dst = ei + NE;

    // workspace layout (all 4B elems; sized so bufA/bufB stay 16B aligned)
    int* cnt      = (int*)d_ws;                 // N
    int* offs     = cnt + NN;                   // N+16 (padded)
    int* cursor   = offs + NN + 16;             // N
    int* csr_src  = cursor + NN;                // E
    float* dinv   = (float*)(csr_src + NE);     // N
    float* bufA   = dinv + NN;                  // N*128
    float* bufB   = bufA + (size_t)NN * HIDN;   // N*128

    const int B256 = 256;

    // CSR build + dinv
    zero_cnt_kernel<<<(NN + 255) / 256, B256, 0, stream>>>(cnt, NN);
    count_kernel<<<(NE + 255) / 256, B256, 0, stream>>>(dst, cnt, NE);
    scan_kernel<<<1, 1024, 0, stream>>>(cnt, offs, cursor, dinv, NN);
    fill_kernel<<<(NE + 255) / 256, B256, 0, stream>>>(src, dst, cursor, csr_src, NE);

    // ---- layer 1: hs0 = (x @ W0) * dinv -> bufA; h1 = relu(agg + b0) -> bufB
    gemm_dinv_kernel<FIN, HIDN, 64, 4, 8><<<(NN + 63) / 64, B256, 0, stream>>>(x, W0, dinv, bufA, NN);
    aggregate128_kernel<true><<<(NN + 3) / 4, B256, 0, stream>>>(offs, csr_src, dinv, bufA, b0, bufB, NN);

    // ---- layer 2: hs1 = (h1 @ W1) * dinv -> bufA; h2 = relu(agg + b1) -> bufB
    gemm_dinv_kernel<HIDN, HIDN, 64, 4, 8><<<(NN + 63) / 64, B256, 0, stream>>>(bufB, W1, dinv, bufA, NN);
    aggregate128_kernel<true><<<(NN + 3) / 4, B256, 0, stream>>>(offs, csr_src, dinv, bufA, b1, bufB, NN);

    // ---- layer 3: hs2 = (h2 @ W2) * dinv -> bufA (N x 16); out = agg + b2
    gemm_dinv_kernel<HIDN, NCLS, 256, 4, 4><<<(NN + 255) / 256, B256, 0, stream>>>(bufB, W2, dinv, bufA, NN);
    aggregate16_kernel<<<(NN + 15) / 16, B256, 0, stream>>>(offs, csr_src, dinv, bufA, b2, out, NN);
}

// Round 17
// 545.156 us; speedup vs baseline: 5.8278x; 1.2618x over previous
//
#include <hip/hip_runtime.h>
#include <math.h>

// Problem constants (match reference)
#define NN 50000
#define FIN 512
#define HIDN 128
#define NCLS 16
#define NE 800000

#define SCAN_BLK 256
#define SCAN_NBLK ((NN + SCAN_BLK - 1) / SCAN_BLK)   // 196

// ---------------- CSR build ----------------

__global__ void zero_cnt_kernel(int* __restrict__ cnt, int n) {
    int i = blockIdx.x * blockDim.x + threadIdx.x;
    if (i < n) cnt[i] = 0;
}

__global__ void count_kernel(const int* __restrict__ dst, int* __restrict__ cnt, int e) {
    int i = blockIdx.x * blockDim.x + threadIdx.x;
    if (i < e) atomicAdd(&cnt[dst[i]], 1);
}

// ---- 3-pass parallel scan over cnt[0..NN) ----
// Pass A: per-block exclusive scan (in-block) + block sums.
__global__ __launch_bounds__(SCAN_BLK) void scan_blocks_kernel(
    const int* __restrict__ cnt, int* __restrict__ eoff, int* __restrict__ bsum, int n) {
    __shared__ int sdata[SCAN_BLK];
    const int tid = threadIdx.x;
    const int i = blockIdx.x * SCAN_BLK + tid;
    int v = (i < n) ? cnt[i] : 0;
    sdata[tid] = v;
    __syncthreads();
    for (int off = 1; off < SCAN_BLK; off <<= 1) {
        int t = (tid >= off) ? sdata[tid - off] : 0;
        __syncthreads();
        sdata[tid] += t;
        __syncthreads();
    }
    if (i < n) eoff[i] = sdata[tid] - v;                 // in-block exclusive
    if (tid == SCAN_BLK - 1) bsum[blockIdx.x] = sdata[tid];  // block total
}

// Pass B: single block scans the block sums (exclusive, in place). nb <= 256.
__global__ __launch_bounds__(256) void scan_bsum_kernel(int* __restrict__ bsum, int nb) {
    __shared__ int sdata[256];
    const int tid = threadIdx.x;
    int v = (tid < nb) ? bsum[tid] : 0;
    sdata[tid] = v;
    __syncthreads();
    for (int off = 1; off < 256; off <<= 1) {
        int t = (tid >= off) ? sdata[tid - off] : 0;
        __syncthreads();
        sdata[tid] += t;
        __syncthreads();
    }
    if (tid < nb) bsum[tid] = sdata[tid] - v;            // exclusive
}

// Pass C: combine + emit offs/cursor/dinv. offs[NN] = NE (constant: all dsts in-range).
__global__ void scan_finalize_kernel(
    const int* __restrict__ cnt, const int* __restrict__ eoff, const int* __restrict__ bsum,
    int* __restrict__ offs, int* __restrict__ cursor, float* __restrict__ dinv, int n) {
    int i = blockIdx.x * blockDim.x + threadIdx.x;
    if (i < n) {
        int o = eoff[i] + bsum[i / SCAN_BLK];
        offs[i] = o;
        cursor[i] = o;
        dinv[i] = 1.0f / sqrtf((float)(cnt[i] + 1));     // +1 self loop
    }
    if (i == 0) offs[n] = NE;
}

__global__ void fill_kernel(const int* __restrict__ src, const int* __restrict__ dst,
                            int* __restrict__ cursor, int* __restrict__ csr_src, int e) {
    int i = blockIdx.x * blockDim.x + threadIdx.x;
    if (i < e) {
        int pos = atomicAdd(&cursor[dst[i]], 1);
        csr_src[pos] = src[i];
    }
}

// ---------------- tiled f32 GEMM with dinv-scaled epilogue ----------------
// C[r][:] = (A[r][:] @ W) * dinv[r]

template<int KIN, int KOUT, int BM, int TM, int TN>
__global__ __launch_bounds__(256) void gemm_dinv_kernel(
    const float* __restrict__ A, const float* __restrict__ W,
    const float* __restrict__ dinv, float* __restrict__ C, int nrows) {
    constexpr int BK = 32;
    constexpr int CT = KOUT / TN;   // col thread-groups
    constexpr int RT = 256 / CT;    // row thread-groups
    static_assert(RT * TM == BM, "tile mismatch");

    __shared__ float sAT[BK][BM + 4];   // A transposed: sAT[k][row]
    __shared__ float sW[BK][KOUT];      // W chunk

    const int tid = threadIdx.x;
    const int tx = tid % CT;
    const int ty = tid / CT;
    const int row0 = blockIdx.x * BM;

    float acc[TM][TN];
#pragma unroll
    for (int r = 0; r < TM; ++r)
#pragma unroll
        for (int c = 0; c < TN; ++c) acc[r][c] = 0.0f;

    for (int k0 = 0; k0 < KIN; k0 += BK) {
        constexpr int AF4 = BM * BK / 4;
#pragma unroll
        for (int i = tid; i < AF4; i += 256) {
            int r = i / (BK / 4);
            int kq = i % (BK / 4);
            float4 v = make_float4(0.f, 0.f, 0.f, 0.f);
            int gr = row0 + r;
            if (gr < nrows)
                v = *(const float4*)&A[(size_t)gr * KIN + k0 + kq * 4];
            sAT[kq * 4 + 0][r] = v.x;
            sAT[kq * 4 + 1][r] = v.y;
            sAT[kq * 4 + 2][r] = v.z;
            sAT[kq * 4 + 3][r] = v.w;
        }
        constexpr int WF4 = BK * KOUT / 4;
#pragma unroll
        for (int i = tid; i < WF4; i += 256) {
            int k = i / (KOUT / 4);
            int c = i % (KOUT / 4);
            *(float4*)&sW[k][c * 4] = *(const float4*)&W[(size_t)(k0 + k) * KOUT + c * 4];
        }
        __syncthreads();

#pragma unroll
        for (int k = 0; k < BK; ++k) {
            float a[TM];
            float w[TN];
            *(float4*)&a[0] = *(const float4*)&sAT[k][ty * TM];
#pragma unroll
            for (int j = 0; j < TN; j += 4)
                *(float4*)&w[j] = *(const float4*)&sW[k][tx * TN + j];
#pragma unroll
            for (int r = 0; r < TM; ++r)
#pragma unroll
                for (int c = 0; c < TN; ++c)
                    acc[r][c] = fmaf(a[r], w[c], acc[r][c]);
        }
        __syncthreads();
    }

#pragma unroll
    for (int r = 0; r < TM; ++r) {
        int gr = row0 + ty * TM + r;
        if (gr < nrows) {
            float s = dinv[gr];
#pragma unroll
            for (int c = 0; c < TN; c += 4) {
                float4 v;
                v.x = acc[r][c + 0] * s;
                v.y = acc[r][c + 1] * s;
                v.z = acc[r][c + 2] * s;
                v.w = acc[r][c + 3] * s;
                *(float4*)&C[(size_t)gr * KOUT + tx * TN + c] = v;
            }
        }
    }
}

// ---------------- CSR aggregate + bias (+relu) ----------------
// out[d] = (hs[d] + sum_{s in N(d)} hs[s]) * dinv[d] + bias    (hs carries dinv[src])

// 128-wide: one 64-lane wave per node, float2 per lane. 2-deep ILP on the
// neighbor loop so consecutive gathers pipeline (loop is L2-latency-bound).
template<bool RELU>
__global__ __launch_bounds__(256) void aggregate128_kernel(
    const int* __restrict__ offs, const int* __restrict__ csr_src,
    const float* __restrict__ dinv, const float* __restrict__ hs,
    const float* __restrict__ bias, float* __restrict__ outp, int n) {
    int node = blockIdx.x * 4 + (threadIdx.x >> 6);
    int lane = threadIdx.x & 63;
    if (node >= n) return;
    int beg = offs[node], end = offs[node + 1];
    float2 acc0 = *(const float2*)&hs[(size_t)node * HIDN + lane * 2];  // self
    float2 acc1 = make_float2(0.f, 0.f);
    int j = beg;
    for (; j + 1 < end; j += 2) {
        int s0 = csr_src[j];
        int s1 = csr_src[j + 1];
        float2 v0 = *(const float2*)&hs[(size_t)s0 * HIDN + lane * 2];
        float2 v1 = *(const float2*)&hs[(size_t)s1 * HIDN + lane * 2];
        acc0.x += v0.x; acc0.y += v0.y;
        acc1.x += v1.x; acc1.y += v1.y;
    }
    if (j < end) {
        int s = csr_src[j];
        float2 v = *(const float2*)&hs[(size_t)s * HIDN + lane * 2];
        acc0.x += v.x; acc0.y += v.y;
    }
    float w = dinv[node];
    float2 bb = *(const float2*)&bias[lane * 2];
    float ox = (acc0.x + acc1.x) * w + bb.x;
    float oy = (acc0.y + acc1.y) * w + bb.y;
    if (RELU) { ox = fmaxf(ox, 0.f); oy = fmaxf(oy, 0.f); }
    *(float2*)&outp[(size_t)node * HIDN + lane * 2] = make_float2(ox, oy);
}

// 16-wide: 16 lanes per node, one float per lane.
__global__ __launch_bounds__(256) void aggregate16_kernel(
    const int* __restrict__ offs, const int* __restrict__ csr_src,
    const float* __restrict__ dinv, const float* __restrict__ hs,
    const float* __restrict__ bias, float* __restrict__ outp, int n) {
    int node = blockIdx.x * 16 + (threadIdx.x >> 4);
    int lane = threadIdx.x & 15;
    if (node >= n) return;
    int beg = offs[node], end = offs[node + 1];
    float acc0 = hs[(size_t)node * NCLS + lane];   // self
    float acc1 = 0.f;
    int j = beg;
    for (; j + 1 < end; j += 2) {
        int s0 = csr_src[j];
        int s1 = csr_src[j + 1];
        acc0 += hs[(size_t)s0 * NCLS + lane];
        acc1 += hs[(size_t)s1 * NCLS + lane];
    }
    if (j < end) acc0 += hs[(size_t)csr_src[j] * NCLS + lane];
    outp[(size_t)node * NCLS + lane] = (acc0 + acc1) * dinv[node] + bias[lane];
}

// ---------------- launch ----------------

extern "C" void kernel_launch(void* const* d_in, const int* in_sizes, int n_in,
                              void* d_out, int out_size, void* d_ws, size_t ws_size,
                              hipStream_t stream) {
    const float* x  = (const float*)d_in[0];
    const int* ei   = (const int*)d_in[1];       // [2][E]: first E = src, next E = dst
    const float* W0 = (const float*)d_in[2];
    const float* b0 = (const float*)d_in[3];
    const float* W1 = (const float*)d_in[4];
    const float* b1 = (const float*)d_in[5];
    const float* W2 = (const float*)d_in[6];
    const float* b2 = (const float*)d_in[7];
    float* out = (float*)d_out;

    const int* src = ei;
    const int* dst = ei + NE;

    // workspace layout (all 4B elems; sized so bufA/bufB stay 16B aligned)
    int* cnt      = (int*)d_ws;                 // N
    int* offs     = cnt + NN;                   // N+16 (padded)
    int* cursor   = offs + NN + 16;             // N
    int* csr_src  = cursor + NN;                // E
    float* dinv   = (float*)(csr_src + NE);     // N
    int* eoff     = (int*)(dinv + NN);          // N (scan temp)
    int* bsum     = eoff + NN;                  // SCAN_NBLK (+pad to 16)
    float* bufA   = (float*)(bsum + 256);       // N*128
    float* bufB   = bufA + (size_t)NN * HIDN;   // N*128

    const int B256 = 256;

    // CSR build + dinv (3-pass parallel scan)
    zero_cnt_kernel<<<(NN + 255) / 256, B256, 0, stream>>>(cnt, NN);
    count_kernel<<<(NE + 255) / 256, B256, 0, stream>>>(dst, cnt, NE);
    scan_blocks_kernel<<<SCAN_NBLK, SCAN_BLK, 0, stream>>>(cnt, eoff, bsum, NN);
    scan_bsum_kernel<<<1, 256, 0, stream>>>(bsum, SCAN_NBLK);
    scan_finalize_kernel<<<(NN + 255) / 256, B256, 0, stream>>>(cnt, eoff, bsum, offs, cursor, dinv, NN);
    fill_kernel<<<(NE + 255) / 256, B256, 0, stream>>>(src, dst, cursor, csr_src, NE);

    // ---- layer 1: hs0 = (x @ W0) * dinv -> bufA; h1 = relu(agg + b0) -> bufB
    gemm_dinv_kernel<FIN, HIDN, 64, 4, 8><<<(NN + 63) / 64, B256, 0, stream>>>(x, W0, dinv, bufA, NN);
    aggregate128_kernel<true><<<(NN + 3) / 4, B256, 0, stream>>>(offs, csr_src, dinv, bufA, b0, bufB, NN);

    // ---- layer 2: hs1 = (h1 @ W1) * dinv -> bufA; h2 = relu(agg + b1) -> bufB
    gemm_dinv_kernel<HIDN, HIDN, 64, 4, 8><<<(NN + 63) / 64, B256, 0, stream>>>(bufB, W1, dinv, bufA, NN);
    aggregate128_kernel<true><<<(NN + 3) / 4, B256, 0, stream>>>(offs, csr_src, dinv, bufA, b1, bufB, NN);

    // ---- layer 3: hs2 = (h2 @ W2) * dinv -> bufA (N x 16); out = agg + b2
    gemm_dinv_kernel<HIDN, NCLS, 256, 4, 4><<<(NN + 255) / 256, B256, 0, stream>>>(bufB, W2, dinv, bufA, NN);
    aggregate16_kernel<<<(NN + 15) / 16, B256, 0, stream>>>(offs, csr_src, dinv, bufA, b2, out, NN);
}